// Round 2
// baseline (453.864 us; speedup 1.0000x reference)
//
#include <hip/hip_runtime.h>

#define D_ 128
#define T_ 24
#define NPB 24576  /* rows per batch b in expert phase: T*H*W */

static __device__ __forceinline__ void load8(const float* p, float* dst){
  float4 a = *(const float4*)p; float4 b = *(const float4*)(p+4);
  dst[0]=a.x;dst[1]=a.y;dst[2]=a.z;dst[3]=a.w;dst[4]=b.x;dst[5]=b.y;dst[6]=b.z;dst[7]=b.w;
}

// ---- transpose conv weights (5,128o,128i,2,2) -> wT[(l*4+p)*128+i][128 o] ----
__global__ void prep_wT(const float* __restrict__ cw, float* __restrict__ wT){
  int idx = blockIdx.x*256 + threadIdx.x;
  if (idx >= 5*4*D_*D_) return;
  int o = idx & 127;
  int i = (idx >> 7) & 127;
  int p = (idx >> 14) & 3;
  int l = idx >> 16;
  int kh = p >> 1, kw = p & 1;
  int src = (((l*D_ + o)*D_ + i)*2 + kh)*2 + kw;
  wT[idx] = cw[src];
}

// ---- one conv layer: 2x2 stride-2 VALID conv + bias + BN + leaky(0.2), NHWC ----
__global__ __launch_bounds__(256)
void conv_layer(const float* __restrict__ in, float* __restrict__ out,
                const float* __restrict__ wT,           // [4][128 i][128 o] this layer
                const float* __restrict__ cb, const float* __restrict__ gam,
                const float* __restrict__ bet, const float* __restrict__ mnp,
                const float* __restrict__ vrp, int n_pix, int Hout, int Wout)
{
  __shared__ float xs[64][33];
  __shared__ float wt[32][128];
  const int t = threadIdx.x;
  const int tile0 = blockIdx.x * 64;
  const int tr = t >> 4, tc = t & 15;
  const int Hin = Hout*2, Win = Wout*2;

  float acc[4][8];
#pragma unroll
  for (int i=0;i<4;i++)
#pragma unroll
    for (int j=0;j<8;j++) acc[i][j]=0.f;

  const int lp = t >> 2;
  const int lk = (t & 3) * 8;
  int gp = tile0 + lp; if (gp >= n_pix) gp = n_pix - 1;
  const int hw = Hout*Wout;
  const int n  = gp / hw;
  const int rem = gp - n*hw;
  const int oy = rem / Wout;
  const int ox = rem - oy*Wout;

  const int wil = t >> 3;
  const int wo0 = (t & 7) * 16;

  for (int p4 = 0; p4 < 4; p4++){
    const int kh = p4 >> 1, kw = p4 & 1;
    const float* inbase = in + ((size_t)((n*Hin + 2*oy + kh)*Win) + (2*ox + kw))*D_;
    const float* wbase = wT + (size_t)p4*16384;
    for (int c = 0; c < 4; c++){
      __syncthreads();
      load8(inbase + c*32 + lk, &xs[lp][lk]);
      {
        const float* src = wbase + (size_t)(c*32 + wil)*D_ + wo0;
        float* dst = &wt[wil][wo0];
#pragma unroll
        for (int m=0;m<16;m+=4){ float4 v = *(const float4*)(src+m); *(float4*)(dst+m) = v; }
      }
      __syncthreads();
#pragma unroll
      for (int k=0;k<32;k++){
        float a[4];
#pragma unroll
        for (int i=0;i<4;i++) a[i] = xs[tr*4+i][k];
        float4 w0 = *(const float4*)&wt[k][tc*8];
        float4 w1 = *(const float4*)&wt[k][tc*8+4];
        float w[8] = {w0.x,w0.y,w0.z,w0.w,w1.x,w1.y,w1.z,w1.w};
#pragma unroll
        for (int i=0;i<4;i++)
#pragma unroll
          for (int j=0;j<8;j++) acc[i][j] = fmaf(a[i], w[j], acc[i][j]);
      }
    }
  }
  float cbv[8], sc[8], btv[8], mnv[8];
#pragma unroll
  for (int j=0;j<8;j++){
    int o = tc*8+j;
    cbv[j] = cb[o];
    sc[j]  = gam[o] * rsqrtf(vrp[o] + 1e-5f);
    btv[j] = bet[o];
    mnv[j] = mnp[o];
  }
#pragma unroll
  for (int i=0;i<4;i++){
    int pix = tile0 + tr*4 + i;
    if (pix < n_pix){
      float vals[8];
#pragma unroll
      for (int j=0;j<8;j++){
        float v = acc[i][j] + cbv[j];
        v = sc[j]*(v - mnv[j]) + btv[j];
        vals[j] = v > 0.f ? v : 0.2f*v;
      }
      float* op = out + (size_t)pix*D_ + tc*8;
      *(float4*)op     = make_float4(vals[0],vals[1],vals[2],vals[3]);
      *(float4*)(op+4) = make_float4(vals[4],vals[5],vals[6],vals[7]);
    }
  }
}

// ---- fuse dot + rFFT(1..12) + logits + top-2 softmax gates ----
__global__ void gate_kernel(const float* __restrict__ z, const float* __restrict__ fw,
                            const float* __restrict__ fb, const float* __restrict__ wg,
                            float* __restrict__ gbuf)
{
  __shared__ float s[96];
  __shared__ float amp[4][12];
  __shared__ float logits[4][7];
  const int t = threadIdx.x;
  if (t < 96){
    float a = 0.f;
    for (int d=0; d<D_; d++) a = fmaf(z[t*D_+d], fw[d], a);
    s[t] = a + fb[0];
  }
  __syncthreads();
  if (t < 48){
    const int b = t / 12, kf = (t % 12) + 1;
    float re=0.f, im=0.f;
    for (int tt=0; tt<T_; tt++){
      int ph = (kf*tt) % T_;
      float ang = (float)ph * (6.283185307179586f / (float)T_);
      re = fmaf(s[b*T_+tt], cosf(ang), re);
      im = fmaf(s[b*T_+tt], sinf(ang), im);
    }
    amp[b][t%12] = sqrtf(re*re + im*im) * 0.20412414523193150f; // ortho: 1/sqrt(24)
  }
  __syncthreads();
  if (t < 28){
    const int b = t/7, e = t - (t/7)*7;
    float a = 0.f;
    for (int k=0;k<12;k++) a = fmaf(amp[b][k], wg[k*7+e], a);
    logits[b][e] = a;
  }
  __syncthreads();
  if (t < 4){
    const int b = t;
    int i0=0; float v0=logits[b][0];
    for (int e=1;e<7;e++){ float v=logits[b][e]; if (v > v0){ v0=v; i0=e; } }
    int i1=-1; float v1=-3.4e38f;
    for (int e=0;e<7;e++){ if (e==i0) continue; float v=logits[b][e]; if (v > v1){ v1=v; i1=e; } }
    float ed = expf(v1 - v0);
    gbuf[b*4+0] = 1.f/(1.f+ed);
    gbuf[b*4+1] = ed/(1.f+ed);
    ((int*)gbuf)[b*4+2] = i0;
    ((int*)gbuf)[b*4+3] = i1;
  }
}

// ---- out = log(g0*exp(x@W_e0+b_e0) + g1*exp(x@W_e1+b_e1)) ----
__global__ __launch_bounds__(256)
void expert_kernel(const float* __restrict__ x, const float* __restrict__ ew,
                   const float* __restrict__ eb, const float* __restrict__ gbuf,
                   float* __restrict__ outp)
{
  __shared__ float xs[64][129];
  __shared__ float wt[32][128];
  const int t = threadIdx.x;
  const size_t row0 = (size_t)blockIdx.x * 64;
  const int b = (int)(row0 / NPB);
  const float g0 = gbuf[b*4+0], g1 = gbuf[b*4+1];
  const int e0 = ((const int*)gbuf)[b*4+2];
  const int e1 = ((const int*)gbuf)[b*4+3];

  {
    const int p = t >> 2, k0 = (t & 3) * 32;
    const float* src = x + (row0 + p)*D_ + k0;
#pragma unroll
    for (int m=0;m<32;m+=8) load8(src + m, &xs[p][k0+m]);
  }
  const int tr = t >> 4, tc = t & 15;
  const int wil = t >> 3, wo0 = (t & 7)*16;

  float comb[4][8];
#pragma unroll
  for (int i=0;i<4;i++)
#pragma unroll
    for (int j=0;j<8;j++) comb[i][j]=0.f;

  for (int pass=0; pass<2; pass++){
    const int e = pass ? e1 : e0;
    const float ge = pass ? g1 : g0;
    float acc[4][8];
#pragma unroll
    for (int i=0;i<4;i++)
#pragma unroll
      for (int j=0;j<8;j++) acc[i][j]=0.f;
    for (int c=0;c<4;c++){
      __syncthreads();
      {
        const float* src = ew + (size_t)e*16384 + (size_t)(c*32 + wil)*D_ + wo0;
        load8(src,     &wt[wil][wo0]);
        load8(src + 8, &wt[wil][wo0+8]);
      }
      __syncthreads();
#pragma unroll
      for (int k=0;k<32;k++){
        const int kg = c*32 + k;
        float a[4];
#pragma unroll
        for (int i=0;i<4;i++) a[i] = xs[tr*4+i][kg];
        float4 w0 = *(const float4*)&wt[k][tc*8];
        float4 w1 = *(const float4*)&wt[k][tc*8+4];
        float w[8] = {w0.x,w0.y,w0.z,w0.w,w1.x,w1.y,w1.z,w1.w};
#pragma unroll
        for (int i=0;i<4;i++)
#pragma unroll
          for (int j=0;j<8;j++) acc[i][j] = fmaf(a[i], w[j], acc[i][j]);
      }
    }
#pragma unroll
    for (int j=0;j<8;j++){
      float be = eb[e*D_ + tc*8 + j];
#pragma unroll
      for (int i=0;i<4;i++) comb[i][j] += ge * expf(acc[i][j] + be);
    }
  }
#pragma unroll
  for (int i=0;i<4;i++){
    float vals[8];
#pragma unroll
    for (int j=0;j<8;j++){
      float cv = comb[i][j];
      if (cv == 0.f) cv = 2.220446049250313e-16f;
      vals[j] = logf(cv);
    }
    float* op = outp + (row0 + tr*4 + i)*D_ + tc*8;
    *(float4*)op     = make_float4(vals[0],vals[1],vals[2],vals[3]);
    *(float4*)(op+4) = make_float4(vals[4],vals[5],vals[6],vals[7]);
  }
}

extern "C" void kernel_launch(void* const* d_in, const int* in_sizes, int n_in,
                              void* d_out, int out_size, void* d_ws, size_t ws_size,
                              hipStream_t stream)
{
  const float* x   = (const float*)d_in[0];
  const float* cw  = (const float*)d_in[1];
  const float* cb  = (const float*)d_in[2];
  const float* gam = (const float*)d_in[3];
  const float* bet = (const float*)d_in[4];
  const float* mn  = (const float*)d_in[5];
  const float* vr  = (const float*)d_in[6];
  const float* fw  = (const float*)d_in[7];
  const float* fb  = (const float*)d_in[8];
  const float* wg  = (const float*)d_in[9];
  const float* ew  = (const float*)d_in[10];
  const float* eb  = (const float*)d_in[11];
  float* out = (float*)d_out;

  // Scratch lives inside d_out (50.3 MB fp32): fully overwritten by expert_kernel at the end.
  // wT: 1,310,720 B | bufA: 12,582,912 B | bufB: 3,145,728 B  => 17.0 MB < 50.3 MB
  char* sb = (char*)d_out;
  float* wT   = (float*)sb;
  float* bufA = (float*)(sb + 1310720);
  float* bufB = (float*)(sb + 13893632);
  float* gbuf = (float*)d_ws;   // 64 B: must survive expert_kernel's d_out overwrite

  prep_wT<<<1280, 256, 0, stream>>>(cw, wT);
  conv_layer<<<384, 256, 0, stream>>>(x,    bufA, wT,          cb,     gam,     bet,     mn,     vr,     24576, 16, 16);
  conv_layer<<< 96, 256, 0, stream>>>(bufA, bufB, wT + 65536,  cb+128, gam+128, bet+128, mn+128, vr+128,  6144,  8,  8);
  conv_layer<<< 24, 256, 0, stream>>>(bufB, bufA, wT + 131072, cb+256, gam+256, bet+256, mn+256, vr+256,  1536,  4,  4);
  conv_layer<<<  6, 256, 0, stream>>>(bufA, bufB, wT + 196608, cb+384, gam+384, bet+384, mn+384, vr+384,   384,  2,  2);
  conv_layer<<<  2, 256, 0, stream>>>(bufB, bufA, wT + 262144, cb+512, gam+512, bet+512, mn+512, vr+512,    96,  1,  1);
  gate_kernel<<<1, 128, 0, stream>>>(bufA, fw, fb, wg, gbuf);
  expert_kernel<<<1536, 256, 0, stream>>>(x, ew, eb, gbuf, out);
}

// Round 3
// 293.773 us; speedup vs baseline: 1.5449x; 1.5449x over previous
//
#include <hip/hip_runtime.h>

#define D_ 128
#define T_ 24
#define NPB 24576  /* rows per batch b in expert phase: T*H*W */

typedef __attribute__((ext_vector_type(8))) short bf16x8;
typedef __attribute__((ext_vector_type(4))) float f32x4;

static __device__ __forceinline__ unsigned short f2b(float f){
  union{float f; unsigned u;} c; c.f = f;
  unsigned r = c.u + 0x7FFFu + ((c.u>>16)&1u);   // RNE; inputs finite
  return (unsigned short)(r>>16);
}
static __device__ __forceinline__ float b2f(unsigned short u){
  union{unsigned u; float f;} c; c.u = ((unsigned)u)<<16; return c.f;
}
static __device__ __forceinline__ void load8(const float* p, float* dst){
  float4 a = *(const float4*)p; float4 b = *(const float4*)(p+4);
  dst[0]=a.x;dst[1]=a.y;dst[2]=a.z;dst[3]=a.w;dst[4]=b.x;dst[5]=b.y;dst[6]=b.z;dst[7]=b.w;
}
static __device__ __forceinline__ bf16x8 cvt8(const float* f){
  bf16x8 h;
#pragma unroll
  for (int i=0;i<8;i++) h[i] = (short)f2b(f[i]);
  return h;
}
static __device__ __forceinline__ void split8(const float* f, bf16x8* hh, bf16x8* ll){
  bf16x8 h, l;
#pragma unroll
  for (int i=0;i<8;i++){
    unsigned short hu = f2b(f[i]);
    h[i] = (short)hu;
    l[i] = (short)f2b(f[i] - b2f(hu));
  }
  *hh = h; *ll = l;
}

// ---- transpose conv weights (5,128o,128i,2,2) -> wT[(l*4+p)*128+i][128 o] ----
__global__ void prep_wT(const float* __restrict__ cw, float* __restrict__ wT){
  int idx = blockIdx.x*256 + threadIdx.x;
  if (idx >= 5*4*D_*D_) return;
  int o = idx & 127;
  int i = (idx >> 7) & 127;
  int p = (idx >> 14) & 3;
  int l = idx >> 16;
  int kh = p >> 1, kw = p & 1;
  int src = (((l*D_ + o)*D_ + i)*2 + kh)*2 + kw;
  wT[idx] = cw[src];
}

// ---- conv layer via split-bf16 MFMA: 2x2 s2 VALID conv + bias + BN + leaky, NHWC ----
// A[m][k]=input pixel-tap channels (hi+lo), B[k][n]=wT (hi+lo); 3-term product => ~fp32 accuracy.
__global__ __launch_bounds__(256)
void conv_mfma(const float* __restrict__ in, float* __restrict__ out,
               const float* __restrict__ wTl,  // [4 taps][128 k][128 n] fp32, this layer
               const float* __restrict__ cb, const float* __restrict__ gam,
               const float* __restrict__ bet, const float* __restrict__ mnp,
               const float* __restrict__ vrp, int n_pix, int Hout, int Wout)
{
  __shared__ short xh[64*136];   // [row][k], padded row stride 136 shorts (16B-aligned, 2-way banks)
  __shared__ short xl[64*136];
  __shared__ short wh[128*72];   // [n][k-local 64 of current half], stride 72 shorts
  __shared__ short wl[128*72];
  const int t = threadIdx.x;
  const int wave = t>>6, lane = t&63, quad = lane>>4, l16 = lane&15;
  const int row0 = blockIdx.x*64;
  const int Hin = Hout*2, Win = Wout*2;

  // xs staging mapping: 4 threads per row, 32 k each
  const int sr  = t>>2, skb = (t&3)*32;
  int gp = row0 + sr; if (gp > n_pix-1) gp = n_pix-1;
  const int hw = Hout*Wout;
  const int nimg = gp/hw; const int rem = gp - nimg*hw;
  const int oy = rem/Wout, ox = rem - oy*Wout;
  // ws staging mapping: 4 n × 8 k per thread per half
  const int wn0 = (t&31)*4, wk0 = (t>>5)*8;

  f32x4 acc[8];
#pragma unroll
  for (int ng=0; ng<8; ng++) acc[ng] = (f32x4){0.f,0.f,0.f,0.f};

  for (int tap=0; tap<4; ++tap){
    const int kh = tap>>1, kw = tap&1;
    const float* xrow = in + ((size_t)((nimg*Hin + 2*oy + kh)*Win) + (2*ox + kw))*D_;
    __syncthreads();                       // previous tap's LDS reads done
    // stage x tile (full K=128) hi/lo
#pragma unroll
    for (int g=0; g<4; ++g){
      float f[8]; load8(xrow + skb + g*8, f);
      bf16x8 hh, ll; split8(f, &hh, &ll);
      *(bf16x8*)&xh[sr*136 + skb + g*8] = hh;
      *(bf16x8*)&xl[sr*136 + skb + g*8] = ll;
    }
    for (int h=0; h<2; ++h){
      if (h) __syncthreads();              // half-0 reads of wh/wl done
      // stage W half (64 k), transposed to [n][k], hi/lo
      {
        float4 v[8];
#pragma unroll
        for (int kk=0; kk<8; ++kk)
          v[kk] = *(const float4*)&wTl[(size_t)(tap*128 + h*64 + wk0 + kk)*D_ + wn0];
#pragma unroll
        for (int n=0; n<4; ++n){
          float f[8];
#pragma unroll
          for (int kk=0; kk<8; ++kk) f[kk] = ((const float*)&v[kk])[n];
          bf16x8 hh, ll; split8(f, &hh, &ll);
          *(bf16x8*)&wh[(wn0+n)*72 + wk0] = hh;
          *(bf16x8*)&wl[(wn0+n)*72 + wk0] = ll;
        }
      }
      __syncthreads();
#pragma unroll
      for (int kc=0; kc<2; ++kc){
        const int ko = h*64 + kc*32 + quad*8;
        const int kl = kc*32 + quad*8;
        bf16x8 ah = *(const bf16x8*)&xh[(wave*16 + l16)*136 + ko];
        bf16x8 al = *(const bf16x8*)&xl[(wave*16 + l16)*136 + ko];
#pragma unroll
        for (int ng=0; ng<8; ++ng){
          bf16x8 bh = *(const bf16x8*)&wh[(ng*16 + l16)*72 + kl];
          bf16x8 bl = *(const bf16x8*)&wl[(ng*16 + l16)*72 + kl];
          acc[ng] = __builtin_amdgcn_mfma_f32_16x16x32_bf16(ah, bh, acc[ng], 0,0,0);
          acc[ng] = __builtin_amdgcn_mfma_f32_16x16x32_bf16(ah, bl, acc[ng], 0,0,0);
          acc[ng] = __builtin_amdgcn_mfma_f32_16x16x32_bf16(al, bh, acc[ng], 0,0,0);
        }
      }
    }
  }
  // epilogue: bias + BN + leaky(0.2); D layout: col=l16(+16*ng), row=quad*4+reg
#pragma unroll
  for (int ng=0; ng<8; ++ng){
    const int col = ng*16 + l16;
    const float cbv = cb[col];
    const float sc  = gam[col] * rsqrtf(vrp[col] + 1e-5f);
    const float bt  = bet[col], mv = mnp[col];
#pragma unroll
    for (int reg=0; reg<4; ++reg){
      const int pix = row0 + wave*16 + quad*4 + reg;
      if (pix < n_pix){
        float v = acc[ng][reg] + cbv;
        v = sc*(v - mv) + bt;
        out[(size_t)pix*D_ + col] = v > 0.f ? v : 0.2f*v;
      }
    }
  }
}

// ---- fuse dot + rFFT(1..12) + logits + top-2 softmax gates ----
__global__ void gate_kernel(const float* __restrict__ z, const float* __restrict__ fw,
                            const float* __restrict__ fb, const float* __restrict__ wg,
                            float* __restrict__ gbuf)
{
  __shared__ float s[96];
  __shared__ float amp[4][12];
  __shared__ float logits[4][7];
  const int t = threadIdx.x;
  if (t < 96){
    float a = 0.f;
    for (int d=0; d<D_; d++) a = fmaf(z[t*D_+d], fw[d], a);
    s[t] = a + fb[0];
  }
  __syncthreads();
  if (t < 48){
    const int b = t / 12, kf = (t % 12) + 1;
    float re=0.f, im=0.f;
    for (int tt=0; tt<T_; tt++){
      int ph = (kf*tt) % T_;
      float ang = (float)ph * (6.283185307179586f / (float)T_);
      re = fmaf(s[b*T_+tt], cosf(ang), re);
      im = fmaf(s[b*T_+tt], sinf(ang), im);
    }
    amp[b][t%12] = sqrtf(re*re + im*im) * 0.20412414523193150f; // ortho: 1/sqrt(24)
  }
  __syncthreads();
  if (t < 28){
    const int b = t/7, e = t - (t/7)*7;
    float a = 0.f;
    for (int k=0;k<12;k++) a = fmaf(amp[b][k], wg[k*7+e], a);
    logits[b][e] = a;
  }
  __syncthreads();
  if (t < 4){
    const int b = t;
    int i0=0; float v0=logits[b][0];
    for (int e=1;e<7;e++){ float v=logits[b][e]; if (v > v0){ v0=v; i0=e; } }
    int i1=-1; float v1=-3.4e38f;
    for (int e=0;e<7;e++){ if (e==i0) continue; float v=logits[b][e]; if (v > v1){ v1=v; i1=e; } }
    float ed = expf(v1 - v0);
    gbuf[b*4+0] = 1.f/(1.f+ed);
    gbuf[b*4+1] = ed/(1.f+ed);
    ((int*)gbuf)[b*4+2] = i0;
    ((int*)gbuf)[b*4+3] = i1;
  }
}

// ---- out = log(g0*exp(x@W_e0+b_e0) + g1*exp(x@W_e1+b_e1)) via bf16 MFMA ----
__global__ __launch_bounds__(256)
void expert_mfma(const float* __restrict__ x, const float* __restrict__ ew,
                 const float* __restrict__ eb, const float* __restrict__ gbuf,
                 float* __restrict__ outp)
{
  __shared__ short xs[64*136];     // [row][k=128] bf16
  __shared__ short ws[2*128*72];   // [expert][n][k-local 64 of current half]
  const int t = threadIdx.x;
  const int wave = t>>6, lane = t&63, quad = lane>>4, l16 = lane&15;
  const int row0 = blockIdx.x*64;
  const int b = row0 / NPB;
  const float g0 = gbuf[b*4+0], g1 = gbuf[b*4+1];
  const int e0 = ((const int*)gbuf)[b*4+2];
  const int e1 = ((const int*)gbuf)[b*4+3];

  // stage x tile once (convert fp32 -> bf16)
  {
    const int sr = t>>2, skb = (t&3)*32;
    const float* src = x + (size_t)(row0 + sr)*D_ + skb;
#pragma unroll
    for (int g=0; g<4; ++g){
      float f[8]; load8(src + g*8, f);
      *(bf16x8*)&xs[sr*136 + skb + g*8] = cvt8(f);
    }
  }

  f32x4 acc0[8], acc1[8];
#pragma unroll
  for (int ng=0; ng<8; ng++){ acc0[ng] = (f32x4){0.f,0.f,0.f,0.f}; acc1[ng] = acc0[ng]; }

  const int el = t>>7, r7 = t&127;
  const int n0 = (r7&31)*4, k0 = (r7>>5)*16;
  const int esel = el ? e1 : e0;

  for (int h=0; h<2; ++h){
    if (h) __syncthreads();           // half-0 reads of ws done
    // stage both experts' W half, transposed [n][k]
#pragma unroll
    for (int sub=0; sub<2; ++sub){
      float4 v[8];
#pragma unroll
      for (int kk=0; kk<8; ++kk)
        v[kk] = *(const float4*)&ew[(size_t)esel*16384 + (size_t)(h*64 + k0 + sub*8 + kk)*D_ + n0];
#pragma unroll
      for (int n=0; n<4; ++n){
        float f[8];
#pragma unroll
        for (int kk=0; kk<8; ++kk) f[kk] = ((const float*)&v[kk])[n];
        *(bf16x8*)&ws[(el*128 + n0+n)*72 + k0 + sub*8] = cvt8(f);
      }
    }
    __syncthreads();
#pragma unroll
    for (int kc=0; kc<2; ++kc){
      const int kl = kc*32 + quad*8;
      bf16x8 a = *(const bf16x8*)&xs[(wave*16 + l16)*136 + h*64 + kl];
#pragma unroll
      for (int ng=0; ng<8; ++ng){
        bf16x8 b0 = *(const bf16x8*)&ws[(      ng*16 + l16)*72 + kl];
        bf16x8 b1 = *(const bf16x8*)&ws[(128 + ng*16 + l16)*72 + kl];
        acc0[ng] = __builtin_amdgcn_mfma_f32_16x16x32_bf16(a, b0, acc0[ng], 0,0,0);
        acc1[ng] = __builtin_amdgcn_mfma_f32_16x16x32_bf16(a, b1, acc1[ng], 0,0,0);
      }
    }
  }
  // epilogue
#pragma unroll
  for (int ng=0; ng<8; ++ng){
    const int col = ng*16 + l16;
    const float be0 = eb[e0*D_ + col];
    const float be1 = eb[e1*D_ + col];
#pragma unroll
    for (int reg=0; reg<4; ++reg){
      const int row = row0 + wave*16 + quad*4 + reg;
      float c = g0*expf(acc0[ng][reg] + be0) + g1*expf(acc1[ng][reg] + be1);
      if (c == 0.f) c = 2.220446049250313e-16f;
      outp[(size_t)row*D_ + col] = logf(c);
    }
  }
}

extern "C" void kernel_launch(void* const* d_in, const int* in_sizes, int n_in,
                              void* d_out, int out_size, void* d_ws, size_t ws_size,
                              hipStream_t stream)
{
  const float* x   = (const float*)d_in[0];
  const float* cw  = (const float*)d_in[1];
  const float* cb  = (const float*)d_in[2];
  const float* gam = (const float*)d_in[3];
  const float* bet = (const float*)d_in[4];
  const float* mn  = (const float*)d_in[5];
  const float* vr  = (const float*)d_in[6];
  const float* fw  = (const float*)d_in[7];
  const float* fb  = (const float*)d_in[8];
  const float* wg  = (const float*)d_in[9];
  const float* ew  = (const float*)d_in[10];
  const float* eb  = (const float*)d_in[11];
  float* out = (float*)d_out;

  // Scratch inside d_out (50.3 MB fp32): fully overwritten by expert_mfma at the end.
  // expert_mfma reads only x/ew/eb/gbuf, so no race with its own out-writes.
  char* sb = (char*)d_out;
  float* wT   = (float*)sb;                 // 1,310,720 B
  float* bufA = (float*)(sb + 1310720);     // 12,582,912 B
  float* bufB = (float*)(sb + 13893632);    // 3,145,728 B
  float* gbuf = (float*)d_ws;               // 64 B, survives d_out overwrite

  prep_wT<<<1280, 256, 0, stream>>>(cw, wT);
  conv_mfma<<<384, 256, 0, stream>>>(x,    bufA, wT,          cb,     gam,     bet,     mn,     vr,     24576, 16, 16);
  conv_mfma<<< 96, 256, 0, stream>>>(bufA, bufB, wT + 65536,  cb+128, gam+128, bet+128, mn+128, vr+128,  6144,  8,  8);
  conv_mfma<<< 24, 256, 0, stream>>>(bufB, bufA, wT + 131072, cb+256, gam+256, bet+256, mn+256, vr+256,  1536,  4,  4);
  conv_mfma<<<  6, 256, 0, stream>>>(bufA, bufB, wT + 196608, cb+384, gam+384, bet+384, mn+384, vr+384,   384,  2,  2);
  conv_mfma<<<  2, 256, 0, stream>>>(bufB, bufA, wT + 262144, cb+512, gam+512, bet+512, mn+512, vr+512,    96,  1,  1);
  gate_kernel<<<1, 128, 0, stream>>>(bufA, fw, fb, wg, gbuf);
  expert_mfma<<<1536, 256, 0, stream>>>(x, ew, eb, gbuf, out);
}